// Round 10
// baseline (189.254 us; speedup 1.0000x reference)
//
#include <hip/hip_runtime.h>

#define IN_DIM 128
#define OUT_DIM 128
#define SEGCAP 2048   // per-bucket edge segment capacity (Poisson(1024): safe)

typedef short bf16x8 __attribute__((ext_vector_type(8)));
typedef float f32x4 __attribute__((ext_vector_type(4)));
typedef float f32x2 __attribute__((ext_vector_type(2)));
typedef unsigned int u32x4 __attribute__((ext_vector_type(4)));

__device__ __forceinline__ unsigned short f2bf(float f) {
    union { float f; unsigned int u; } v; v.f = f;
    unsigned int u = v.u;
    u += 0x7FFFu + ((u >> 16) & 1u);   // round-to-nearest-even
    return (unsigned short)(u >> 16);
}

// ---------------------------------------------------------------------------
// K-1: cursor init — segment base for bucket i is i*SEGCAP
// ---------------------------------------------------------------------------
__global__ __launch_bounds__(256) void init_kernel(int* __restrict__ cursor, int nb) {
    int i = blockIdx.x * 256 + threadIdx.x;
    if (i < nb) cursor[i] = i * SEGCAP;
}

// ---------------------------------------------------------------------------
// K0: x f32 -> bf16 (GEMM A-half) AND fp8 e4m3 (gather copy), 8 elems/thread
// ---------------------------------------------------------------------------
__global__ __launch_bounds__(256) void convert_kernel(const float* __restrict__ x,
                                                      unsigned short* __restrict__ xb,
                                                      unsigned char* __restrict__ xq,
                                                      int total8) {
    int i = blockIdx.x * 256 + threadIdx.x;
    if (i >= total8) return;
    const float4* p = (const float4*)x + (size_t)i * 2;
    float4 v0 = p[0], v1 = p[1];
    bf16x8 h;
    h[0] = (short)f2bf(v0.x); h[1] = (short)f2bf(v0.y);
    h[2] = (short)f2bf(v0.z); h[3] = (short)f2bf(v0.w);
    h[4] = (short)f2bf(v1.x); h[5] = (short)f2bf(v1.y);
    h[6] = (short)f2bf(v1.z); h[7] = (short)f2bf(v1.w);
    *(bf16x8*)(xb + (size_t)i * 8) = h;
    int w0 = 0, w1 = 0;
    w0 = __builtin_amdgcn_cvt_pk_fp8_f32(v0.x, v0.y, w0, false);
    w0 = __builtin_amdgcn_cvt_pk_fp8_f32(v0.z, v0.w, w0, true);
    w1 = __builtin_amdgcn_cvt_pk_fp8_f32(v1.x, v1.y, w1, false);
    w1 = __builtin_amdgcn_cvt_pk_fp8_f32(v1.z, v1.w, w1, true);
    uint2 o; o.x = (unsigned int)w0; o.y = (unsigned int)w1;
    *(uint2*)(xq + (size_t)i * 8) = o;
}

// ---------------------------------------------------------------------------
// K0b: W f32 [k][col] -> bf16 transposed Wt [col][k]  (once)
// ---------------------------------------------------------------------------
__global__ __launch_bounds__(256) void convertW_kernel(const float* __restrict__ W,
                                                       unsigned short* __restrict__ Wt) {
    int t = blockIdx.x * 256 + threadIdx.x;   // 0..4095
    int c = t >> 5, kq = t & 31;              // col, k-octet
    bf16x8 h;
#pragma unroll
    for (int i = 0; i < 8; i++) {
        int k = kq * 8 + i;
        h[i] = (short)f2bf(W[(size_t)k * OUT_DIM + c]);
    }
    *(bf16x8*)(Wt + (size_t)c * 256 + kq * 8) = h;
}

// ---------------------------------------------------------------------------
// K3: placement into per-bucket segments (base = bk*SEGCAP, direct atomic
// cursor alloc). payload = (dstlocal<<17)|src.
// ---------------------------------------------------------------------------
__global__ __launch_bounds__(1024) void place_kernel(const int* __restrict__ src,
                                                     const int* __restrict__ dst,
                                                     int* __restrict__ cursor,
                                                     unsigned int* __restrict__ csr_packed,
                                                     int nE, int nb) {
    __shared__ int lcnt[2048];
    __shared__ int lbase[2048];
    const int t = threadIdx.x;
    for (int i = t; i < nb; i += 1024) lcnt[i] = 0;
    __syncthreads();
    const int e0 = blockIdx.x * 16384;
    unsigned int meta[16];
#pragma unroll
    for (int k = 0; k < 16; k++) {
        int e = e0 + k * 1024 + t;
        if (e < nE) {
            int d = dst[e];
            int bk = d >> 6, dl = d & 63;
            int r = atomicAdd(&lcnt[bk], 1);
            meta[k] = ((unsigned)bk << 20) | ((unsigned)dl << 14) | (unsigned)r;
        } else meta[k] = 0xFFFFFFFFu;
    }
    __syncthreads();
    for (int i = t; i < nb; i += 1024) {
        int c = lcnt[i];
        lbase[i] = c ? atomicAdd(&cursor[i], c) : 0;
    }
    __syncthreads();
#pragma unroll
    for (int k = 0; k < 16; k++) {
        if (meta[k] != 0xFFFFFFFFu) {
            int e = e0 + k * 1024 + t;
            unsigned int m = meta[k];
            int bk = m >> 20, dl = (m >> 14) & 63, r = m & 0x3FFF;
            csr_packed[lbase[bk] + r] = ((unsigned)dl << 17) | (unsigned)src[e];
        }
    }
}

// ---------------------------------------------------------------------------
// K4: FUSED per-bucket kernel.
//   Gather restructured: 4 rows in parallel per wave (16-lane group per row,
//   8B/lane = 8 fp8 cols). One load instr = 4 src rows; packed f32x2 adds;
//   masked fully-issued tail (no serialized 2-src loop); no cross-lane
//   combine. GEMM unchanged (zero-barrier, B/x direct from global).
// ---------------------------------------------------------------------------
__global__ __launch_bounds__(256, 6) void fused_kernel(const unsigned short* __restrict__ xb,
                                                       const unsigned char* __restrict__ xq,
                                                       const unsigned short* __restrict__ Wt,
                                                       const unsigned int* __restrict__ csr_packed,
                                                       const int* __restrict__ cursor,
                                                       const float* __restrict__ bias,
                                                       float* __restrict__ out, int nN) {
    __shared__ int bcnt[64];
    __shared__ int bexcl[64];
    __shared__ unsigned int elist[2048];
    __shared__ __align__(16) short Ntile[64 * 136];   // neighbor-mean rows (bf16)

    const int t = threadIdx.x;
    const int lane = t & 63;
    const int wave = t >> 6;
    const int row0 = blockIdx.x * 64;

    const int e0 = blockIdx.x * SEGCAP;
    int n = cursor[blockIdx.x] - e0;
    if (n > SEGCAP) n = SEGCAP;

    if (t < 64) bcnt[t] = 0;
    __syncthreads();

    // ---- load packed edges + bin-rank via LDS atomics
    unsigned int pk[8]; int rk[8];
#pragma unroll
    for (int k = 0; k < 8; k++) {
        int idx = k * 256 + t;
        if (idx < n) {
            unsigned int p = csr_packed[e0 + idx];
            pk[k] = p;
            rk[k] = atomicAdd(&bcnt[(p >> 17) & 63], 1);
        } else pk[k] = 0xFFFFFFFFu;
    }
    __syncthreads();

    // ---- exclusive scan of 64 bins: wave 0, barrier-free shfl scan
    if (wave == 0) {
        int v = bcnt[lane];
        int s = v;
#pragma unroll
        for (int off = 1; off < 64; off <<= 1) {
            int u = __shfl_up(s, off);
            if (lane >= off) s += u;
        }
        bexcl[lane] = s - v;
    }
    __syncthreads();

    // ---- counting-sort src ids into LDS edge list
#pragma unroll
    for (int k = 0; k < 8; k++) {
        if (pk[k] != 0xFFFFFFFFu) {
            int dl = (pk[k] >> 17) & 63;
            elist[bexcl[dl] + rk[k]] = pk[k] & 0x1FFFFu;
        }
    }
    __syncthreads();

    // ---- gather (fp8): 4 rows in parallel per wave.
    //      group g = lane>>4 owns row (wave*16 + set*4 + g);
    //      lane col-octet c = lane&15 covers fp8 cols 8c..8c+7 (8B load).
    {
        const int g = lane >> 4;
        const int c = lane & 15;
#pragma unroll
        for (int set = 0; set < 4; set++) {
            const int r  = wave * 16 + set * 4 + g;
            const int st = bexcl[r];
            const int dg = bcnt[r];
            const int dgm1 = (dg > 0) ? (dg - 1) : 0;
            int maxdg = dg;
            maxdg = max(maxdg, __shfl_xor(maxdg, 16));
            maxdg = max(maxdg, __shfl_xor(maxdg, 32));
            f32x2 a0{0.f, 0.f}, a1{0.f, 0.f}, a2{0.f, 0.f}, a3{0.f, 0.f};
            for (int j = 0; j < maxdg; j += 8) {
#pragma unroll
                for (int u = 0; u < 8; u++) {
                    const int id  = j + u;
                    const int cid = (id < dg) ? id : dgm1;
                    int s = (int)elist[st + cid];
                    s = (dg > 0) ? s : 0;
                    uint2 v = *(const uint2*)(xq + (size_t)s * IN_DIM + c * 8);
                    const bool live = (id < dg);
                    v.x = live ? v.x : 0u;
                    v.y = live ? v.y : 0u;
                    f32x2 p;
                    p = __builtin_amdgcn_cvt_pk_f32_fp8(v.x, false); a0 += p;
                    p = __builtin_amdgcn_cvt_pk_f32_fp8(v.x, true);  a1 += p;
                    p = __builtin_amdgcn_cvt_pk_f32_fp8(v.y, false); a2 += p;
                    p = __builtin_amdgcn_cvt_pk_f32_fp8(v.y, true);  a3 += p;
                }
            }
            const float rd = 1.0f / (float)((dg > 0) ? dg : 1);
            a0 *= rd; a1 *= rd; a2 *= rd; a3 *= rd;
            unsigned int w0, w1, w2, w3;
            asm("v_cvt_pk_bf16_f32 %0, %1, %2" : "=v"(w0) : "v"(a0.x), "v"(a0.y));
            asm("v_cvt_pk_bf16_f32 %0, %1, %2" : "=v"(w1) : "v"(a1.x), "v"(a1.y));
            asm("v_cvt_pk_bf16_f32 %0, %1, %2" : "=v"(w2) : "v"(a2.x), "v"(a2.y));
            asm("v_cvt_pk_bf16_f32 %0, %1, %2" : "=v"(w3) : "v"(a3.x), "v"(a3.y));
            u32x4 o = {w0, w1, w2, w3};
            *(u32x4*)&Ntile[r * 136 + c * 8] = o;
        }
    }
    // NO barrier: each wave's MFMA below reads only its own 16 Ntile rows.

    // ---- GEMM: K=256 (k<128 from global xb, k>=128 from Ntile), B from global Wt
    f32x4 acc[8];
#pragma unroll
    for (int c = 0; c < 8; c++) acc[c] = f32x4{0.f, 0.f, 0.f, 0.f};

    const int arow = wave * 16 + (lane & 15);
    const int koff = (lane >> 4) * 8;
    const int rowc = min(row0 + arow, nN - 1);   // clamp: OOB rows never stored
    const unsigned short* xrow = xb + (size_t)rowc * IN_DIM;
    const unsigned short* wcol = Wt + (size_t)(lane & 15) * 256;   // + c*16*256

#pragma unroll
    for (int kc = 0; kc < 4; kc++) {
#pragma unroll
        for (int ks = 0; ks < 2; ks++) {
            const int kg = kc * 64 + ks * 32 + koff;
            bf16x8 af;
            if (kc < 2) af = *(const bf16x8*)(xrow + kg);
            else        af = *(const bf16x8*)&Ntile[arow * 136 + (kg - 128)];
#pragma unroll
            for (int c = 0; c < 8; c++) {
                bf16x8 bf = *(const bf16x8*)(wcol + (size_t)c * 16 * 256 + kg);
                acc[c] = __builtin_amdgcn_mfma_f32_16x16x32_bf16(af, bf, acc[c], 0, 0, 0);
            }
        }
    }

    // ---- epilogue: C/D layout col=lane&15, row=(lane>>4)*4+reg  [m89]
    const int orow0 = row0 + wave * 16 + (lane >> 4) * 4;
    const int ocol  = lane & 15;
#pragma unroll
    for (int c = 0; c < 8; c++) {
        const float bv = bias[c * 16 + ocol];
#pragma unroll
        for (int r = 0; r < 4; r++) {
            int row = orow0 + r;
            if (row < nN)
                out[(size_t)row * OUT_DIM + c * 16 + ocol] = acc[c][r] + bv;
        }
    }
}

// ---------------------------------------------------------------------------
extern "C" void kernel_launch(void* const* d_in, const int* in_sizes, int n_in,
                              void* d_out, int out_size, void* d_ws, size_t ws_size,
                              hipStream_t stream) {
    const float* x        = (const float*)d_in[0];
    const int*   edge_src = (const int*)d_in[1];
    const int*   edge_dst = (const int*)d_in[2];
    const float* W        = (const float*)d_in[3];
    const float* bias     = (const float*)d_in[4];
    float* out = (float*)d_out;

    const int nN = in_sizes[0] / IN_DIM;   // 100000
    const int nE = in_sizes[1];            // 1600000
    const int nb = (nN + 63) >> 6;         // 1563 buckets

    // ws (~51.3 MB): cursor[2048] int, csr_packed[nb*SEGCAP] u32 (12.8MB),
    //                xb bf16[nN*128] (25.6MB), xq fp8[nN*128] (12.8MB), Wt bf16
    int* cursor = (int*)d_ws;
    unsigned int* csr_packed = (unsigned int*)(cursor + 2048);
    unsigned short* xb = (unsigned short*)(csr_packed + (size_t)nb * SEGCAP);
    unsigned char*  xq = (unsigned char*)(xb + (size_t)nN * IN_DIM);
    unsigned short* Wt = (unsigned short*)(xq + (size_t)nN * IN_DIM);

    init_kernel<<<(nb + 255) / 256, 256, 0, stream>>>(cursor, nb);

    const int total8 = nN * IN_DIM / 8;
    convert_kernel<<<(total8 + 255) / 256, 256, 0, stream>>>(x, xb, xq, total8);
    convertW_kernel<<<16, 256, 0, stream>>>(W, Wt);

    const int eblk = (nE + 16383) / 16384;   // 98
    place_kernel<<<eblk, 1024, 0, stream>>>(edge_src, edge_dst, cursor, csr_packed, nE, nb);
    fused_kernel<<<nb, 256, 0, stream>>>(xb, xq, Wt, csr_packed, cursor, bias, out, nN);
}

// Round 11
// 138.189 us; speedup vs baseline: 1.3695x; 1.3695x over previous
//
#include <hip/hip_runtime.h>

#define IN_DIM 128
#define OUT_DIM 128
#define SEGCAP 2048   // per-bucket edge segment capacity (Poisson(1024): safe)

typedef short bf16x8 __attribute__((ext_vector_type(8)));
typedef float f32x4 __attribute__((ext_vector_type(4)));
typedef float f32x2 __attribute__((ext_vector_type(2)));
typedef unsigned int u32x4 __attribute__((ext_vector_type(4)));

__device__ __forceinline__ unsigned short f2bf(float f) {
    union { float f; unsigned int u; } v; v.f = f;
    unsigned int u = v.u;
    u += 0x7FFFu + ((u >> 16) & 1u);   // round-to-nearest-even
    return (unsigned short)(u >> 16);
}

// ---------------------------------------------------------------------------
// K-1: cursor init — segment base for bucket i is i*SEGCAP
// ---------------------------------------------------------------------------
__global__ __launch_bounds__(256) void init_kernel(int* __restrict__ cursor, int nb) {
    int i = blockIdx.x * 256 + threadIdx.x;
    if (i < nb) cursor[i] = i * SEGCAP;
}

// ---------------------------------------------------------------------------
// K0: x f32 -> fp8 e4m3 gather copy (8 elems/thread)
// ---------------------------------------------------------------------------
__global__ __launch_bounds__(256) void convertq_kernel(const float* __restrict__ x,
                                                       unsigned char* __restrict__ xq,
                                                       int total8) {
    int i = blockIdx.x * 256 + threadIdx.x;
    if (i >= total8) return;
    const float4* p = (const float4*)x + (size_t)i * 2;
    float4 v0 = p[0], v1 = p[1];
    int w0 = 0, w1 = 0;
    w0 = __builtin_amdgcn_cvt_pk_fp8_f32(v0.x, v0.y, w0, false);
    w0 = __builtin_amdgcn_cvt_pk_fp8_f32(v0.z, v0.w, w0, true);
    w1 = __builtin_amdgcn_cvt_pk_fp8_f32(v1.x, v1.y, w1, false);
    w1 = __builtin_amdgcn_cvt_pk_fp8_f32(v1.z, v1.w, w1, true);
    uint2 o; o.x = (unsigned int)w0; o.y = (unsigned int)w1;
    *(uint2*)(xq + (size_t)i * 8) = o;
}

// ---------------------------------------------------------------------------
// K0b: W f32 [k][col] -> bf16 transposed Wt [col][k]  (once)
// ---------------------------------------------------------------------------
__global__ __launch_bounds__(256) void convertW_kernel(const float* __restrict__ W,
                                                       unsigned short* __restrict__ Wt) {
    int t = blockIdx.x * 256 + threadIdx.x;   // 0..4095
    int c = t >> 5, kq = t & 31;              // col, k-octet
    bf16x8 h;
#pragma unroll
    for (int i = 0; i < 8; i++) {
        int k = kq * 8 + i;
        h[i] = (short)f2bf(W[(size_t)k * OUT_DIM + c]);
    }
    *(bf16x8*)(Wt + (size_t)c * 256 + kq * 8) = h;
}

// ---------------------------------------------------------------------------
// K3: placement into per-bucket segments. payload = (dstlocal<<17)|src.
// ---------------------------------------------------------------------------
__global__ __launch_bounds__(1024) void place_kernel(const int* __restrict__ src,
                                                     const int* __restrict__ dst,
                                                     int* __restrict__ cursor,
                                                     unsigned int* __restrict__ csr_packed,
                                                     int nE, int nb) {
    __shared__ int lcnt[2048];
    __shared__ int lbase[2048];
    const int t = threadIdx.x;
    for (int i = t; i < nb; i += 1024) lcnt[i] = 0;
    __syncthreads();
    const int e0 = blockIdx.x * 16384;
    unsigned int meta[16];
#pragma unroll
    for (int k = 0; k < 16; k++) {
        int e = e0 + k * 1024 + t;
        if (e < nE) {
            int d = dst[e];
            int bk = d >> 6, dl = d & 63;
            int r = atomicAdd(&lcnt[bk], 1);
            meta[k] = ((unsigned)bk << 20) | ((unsigned)dl << 14) | (unsigned)r;
        } else meta[k] = 0xFFFFFFFFu;
    }
    __syncthreads();
    for (int i = t; i < nb; i += 1024) {
        int c = lcnt[i];
        lbase[i] = c ? atomicAdd(&cursor[i], c) : 0;
    }
    __syncthreads();
#pragma unroll
    for (int k = 0; k < 16; k++) {
        if (meta[k] != 0xFFFFFFFFu) {
            int e = e0 + k * 1024 + t;
            unsigned int m = meta[k];
            int bk = m >> 20, dl = (m >> 14) & 63, r = m & 0x3FFF;
            csr_packed[lbase[bk] + r] = ((unsigned)dl << 17) | (unsigned)src[e];
        }
    }
}

// ---------------------------------------------------------------------------
// K4a: GATHER-ONLY kernel (diagnostic split). Per-bucket sort + fp8 gather,
// writes neighbor-mean rows (bf16) to global `neigh`. LDS 8.7KB -> 8 blk/CU.
// ---------------------------------------------------------------------------
__global__ __launch_bounds__(256, 8) void gather_kernel(const unsigned char* __restrict__ xq,
                                                        const unsigned int* __restrict__ csr_packed,
                                                        const int* __restrict__ cursor,
                                                        unsigned short* __restrict__ neigh,
                                                        int nN) {
    __shared__ int bcnt[64];
    __shared__ int bexcl[64];
    __shared__ unsigned int elist[2048];

    const int t = threadIdx.x;
    const int lane = t & 63;
    const int wave = t >> 6;
    const int row0 = blockIdx.x * 64;

    const int e0 = blockIdx.x * SEGCAP;
    int n = cursor[blockIdx.x] - e0;
    if (n > SEGCAP) n = SEGCAP;

    if (t < 64) bcnt[t] = 0;
    __syncthreads();

    unsigned int pk[8]; int rk[8];
#pragma unroll
    for (int k = 0; k < 8; k++) {
        int idx = k * 256 + t;
        if (idx < n) {
            unsigned int p = csr_packed[e0 + idx];
            pk[k] = p;
            rk[k] = atomicAdd(&bcnt[(p >> 17) & 63], 1);
        } else pk[k] = 0xFFFFFFFFu;
    }
    __syncthreads();

    if (wave == 0) {
        int v = bcnt[lane];
        int s = v;
#pragma unroll
        for (int off = 1; off < 64; off <<= 1) {
            int u = __shfl_up(s, off);
            if (lane >= off) s += u;
        }
        bexcl[lane] = s - v;
    }
    __syncthreads();

#pragma unroll
    for (int k = 0; k < 8; k++) {
        if (pk[k] != 0xFFFFFFFFu) {
            int dl = (pk[k] >> 17) & 63;
            elist[bexcl[dl] + rk[k]] = pk[k] & 0x1FFFFu;
        }
    }
    __syncthreads();

    // 4 rows in parallel per wave; group g = lane>>4 owns a row;
    // lane octet c = lane&15 covers fp8 cols 8c..8c+7 (8B load).
    const int g = lane >> 4;
    const int c = lane & 15;
#pragma unroll
    for (int set = 0; set < 4; set++) {
        const int r  = wave * 16 + set * 4 + g;
        const int st = bexcl[r];
        const int dg = bcnt[r];
        const int dgm1 = (dg > 0) ? (dg - 1) : 0;
        int maxdg = dg;
        maxdg = max(maxdg, __shfl_xor(maxdg, 16));
        maxdg = max(maxdg, __shfl_xor(maxdg, 32));
        f32x2 a0{0.f, 0.f}, a1{0.f, 0.f}, a2{0.f, 0.f}, a3{0.f, 0.f};
        for (int j = 0; j < maxdg; j += 8) {
#pragma unroll
            for (int u = 0; u < 8; u++) {
                const int id  = j + u;
                const int cid = (id < dg) ? id : dgm1;
                int s = (int)elist[st + cid];
                s = (dg > 0) ? s : 0;
                uint2 v = *(const uint2*)(xq + (size_t)s * IN_DIM + c * 8);
                const bool live = (id < dg);
                v.x = live ? v.x : 0u;
                v.y = live ? v.y : 0u;
                f32x2 p;
                p = __builtin_amdgcn_cvt_pk_f32_fp8(v.x, false); a0 += p;
                p = __builtin_amdgcn_cvt_pk_f32_fp8(v.x, true);  a1 += p;
                p = __builtin_amdgcn_cvt_pk_f32_fp8(v.y, false); a2 += p;
                p = __builtin_amdgcn_cvt_pk_f32_fp8(v.y, true);  a3 += p;
            }
        }
        const float rd = 1.0f / (float)((dg > 0) ? dg : 1);
        a0 *= rd; a1 *= rd; a2 *= rd; a3 *= rd;
        unsigned int w0, w1, w2, w3;
        asm("v_cvt_pk_bf16_f32 %0, %1, %2" : "=v"(w0) : "v"(a0.x), "v"(a0.y));
        asm("v_cvt_pk_bf16_f32 %0, %1, %2" : "=v"(w1) : "v"(a1.x), "v"(a1.y));
        asm("v_cvt_pk_bf16_f32 %0, %1, %2" : "=v"(w2) : "v"(a2.x), "v"(a2.y));
        asm("v_cvt_pk_bf16_f32 %0, %1, %2" : "=v"(w3) : "v"(a3.x), "v"(a3.y));
        u32x4 o = {w0, w1, w2, w3};
        *(u32x4*)(neigh + (size_t)(row0 + r) * IN_DIM + c * 8) = o;   // coalesced 256B/group
    }
}

// ---------------------------------------------------------------------------
// K4b: GEMM kernel (r3-proven structure; B staged by direct bf16 copy from
// pre-transposed Wt — no per-block transpose, no global per-fragment reads).
// ---------------------------------------------------------------------------
__global__ __launch_bounds__(256, 3) void gemm_kernel(const float* __restrict__ x,
                                                      const unsigned short* __restrict__ neigh,
                                                      const unsigned short* __restrict__ Wt,
                                                      const float* __restrict__ bias,
                                                      float* __restrict__ out, int nN) {
    __shared__ __align__(16) short A_s[64 * 264];    // K=256 + 8 pad
    __shared__ __align__(16) short Wt_s[128 * 72];   // 64-k chunk + 8 pad

    const int t = threadIdx.x;
    const int lane = t & 63;
    const int wave = t >> 6;
    const int row0 = blockIdx.x * 64;

    // ---- stage A x-half from f32 x (f2bf on the fly)
#pragma unroll
    for (int p = 0; p < 8; p++) {
        int q = t + p * 256;
        int r = q >> 5, c4 = q & 31;
        int row = row0 + r;
        float4 v = make_float4(0.f, 0.f, 0.f, 0.f);
        if (row < nN) v = *(const float4*)(x + (size_t)row * IN_DIM + c4 * 4);
        unsigned int lo = (unsigned int)f2bf(v.x) | ((unsigned int)f2bf(v.y) << 16);
        unsigned int hi = (unsigned int)f2bf(v.z) | ((unsigned int)f2bf(v.w) << 16);
        uint2 o; o.x = lo; o.y = hi;
        *(uint2*)&A_s[r * 264 + c4 * 4] = o;
    }
    // ---- stage A neigh-half (bf16 direct copy)
#pragma unroll
    for (int p = 0; p < 4; p++) {
        int q = t + p * 256;
        int r = q >> 4, c8 = q & 15;
        int row = row0 + r;
        bf16x8 v = {0, 0, 0, 0, 0, 0, 0, 0};
        if (row < nN) v = *(const bf16x8*)(neigh + (size_t)row * IN_DIM + c8 * 8);
        *(bf16x8*)&A_s[r * 264 + 128 + c8 * 8] = v;
    }

    f32x4 acc[8];
#pragma unroll
    for (int c = 0; c < 8; c++) acc[c] = f32x4{0.f, 0.f, 0.f, 0.f};

    const int arow = wave * 16 + (lane & 15);
    const int koff = (lane >> 4) * 8;

    for (int kc = 0; kc < 4; kc++) {
        __syncthreads();   // A_s ready (kc=0) / prior Wt_s readers done
        // ---- stage Wt chunk: 128 cols x 64 k, direct bf16 copy
#pragma unroll
        for (int p = 0; p < 4; p++) {
            int q = t + p * 256;         // 1024 bf16x8 units
            int col = q >> 3, ko = q & 7;
            *(bf16x8*)&Wt_s[col * 72 + ko * 8] =
                *(const bf16x8*)(Wt + (size_t)col * 256 + kc * 64 + ko * 8);
        }
        __syncthreads();
#pragma unroll
        for (int ks = 0; ks < 2; ks++) {
            const int kloc = ks * 32 + koff;
            bf16x8 af = *(const bf16x8*)&A_s[arow * 264 + kc * 64 + kloc];
#pragma unroll
            for (int c = 0; c < 8; c++) {
                bf16x8 bf = *(const bf16x8*)&Wt_s[(c * 16 + (lane & 15)) * 72 + kloc];
                acc[c] = __builtin_amdgcn_mfma_f32_16x16x32_bf16(af, bf, acc[c], 0, 0, 0);
            }
        }
    }

    // ---- epilogue: C/D layout col=lane&15, row=(lane>>4)*4+reg  [m89]
    const int orow0 = row0 + wave * 16 + (lane >> 4) * 4;
    const int ocol  = lane & 15;
#pragma unroll
    for (int c = 0; c < 8; c++) {
        const float bv = bias[c * 16 + ocol];
#pragma unroll
        for (int r = 0; r < 4; r++) {
            int row = orow0 + r;
            if (row < nN)
                out[(size_t)row * OUT_DIM + c * 16 + ocol] = acc[c][r] + bv;
        }
    }
}

// ---------------------------------------------------------------------------
extern "C" void kernel_launch(void* const* d_in, const int* in_sizes, int n_in,
                              void* d_out, int out_size, void* d_ws, size_t ws_size,
                              hipStream_t stream) {
    const float* x        = (const float*)d_in[0];
    const int*   edge_src = (const int*)d_in[1];
    const int*   edge_dst = (const int*)d_in[2];
    const float* W        = (const float*)d_in[3];
    const float* bias     = (const float*)d_in[4];
    float* out = (float*)d_out;

    const int nN = in_sizes[0] / IN_DIM;   // 100000
    const int nE = in_sizes[1];            // 1600000
    const int nb = (nN + 63) >> 6;         // 1563 buckets

    // ws (~51.3 MB): cursor[2048] int, csr_packed[nb*SEGCAP] u32 (12.8MB),
    //                xq fp8[nN*128] (12.8MB), Wt bf16[128*256] (64KB),
    //                neigh bf16[nb*64*128] (25.6MB)
    int* cursor = (int*)d_ws;
    unsigned int* csr_packed = (unsigned int*)(cursor + 2048);
    unsigned char*  xq = (unsigned char*)(csr_packed + (size_t)nb * SEGCAP);
    unsigned short* Wt = (unsigned short*)(xq + (size_t)nN * IN_DIM);
    unsigned short* neigh = Wt + 128 * 256;

    init_kernel<<<(nb + 255) / 256, 256, 0, stream>>>(cursor, nb);

    const int total8 = nN * IN_DIM / 8;
    convertq_kernel<<<(total8 + 255) / 256, 256, 0, stream>>>(x, xq, total8);
    convertW_kernel<<<16, 256, 0, stream>>>(W, Wt);

    const int eblk = (nE + 16383) / 16384;   // 98
    place_kernel<<<eblk, 1024, 0, stream>>>(edge_src, edge_dst, cursor, csr_packed, nE, nb);
    gather_kernel<<<nb, 256, 0, stream>>>(xq, csr_packed, cursor, neigh, nN);
    gemm_kernel<<<nb, 256, 0, stream>>>(x, neigh, Wt, bias, out, nN);
}

// Round 12
// 134.785 us; speedup vs baseline: 1.4041x; 1.0253x over previous
//
#include <hip/hip_runtime.h>

#define IN_DIM 128
#define OUT_DIM 128
#define SEGCAP 1536   // per-bucket segment capacity (Poisson(1024), 16-sigma safe)

typedef short bf16x8 __attribute__((ext_vector_type(8)));
typedef float f32x4 __attribute__((ext_vector_type(4)));
typedef float f32x2 __attribute__((ext_vector_type(2)));

__device__ __forceinline__ unsigned short f2bf(float f) {
    union { float f; unsigned int u; } v; v.f = f;
    unsigned int u = v.u;
    u += 0x7FFFu + ((u >> 16) & 1u);   // round-to-nearest-even
    return (unsigned short)(u >> 16);
}

// ---------------------------------------------------------------------------
// init: cursor[i] = i*SEGCAP
// ---------------------------------------------------------------------------
__global__ __launch_bounds__(256) void init_kernel(int* __restrict__ cursor, int nb) {
    int i = blockIdx.x * 256 + threadIdx.x;
    if (i < nb) cursor[i] = i * SEGCAP;
}

// ---------------------------------------------------------------------------
// convertq: x f32 -> fp8 e4m3, stored as 4 column-quarter PLANES [nN][32].
// Plane q holds cols 32q..32q+31 -> 3.2MB per plane (fits one XCD L2).
// ---------------------------------------------------------------------------
__global__ __launch_bounds__(256) void convertq_kernel(const float* __restrict__ x,
                                                       unsigned char* __restrict__ xq,
                                                       int nN, int total8) {
    int i = blockIdx.x * 256 + threadIdx.x;
    if (i >= total8) return;
    const float4* p = (const float4*)x + (size_t)i * 2;
    float4 v0 = p[0], v1 = p[1];
    int w0 = 0, w1 = 0;
    w0 = __builtin_amdgcn_cvt_pk_fp8_f32(v0.x, v0.y, w0, false);
    w0 = __builtin_amdgcn_cvt_pk_fp8_f32(v0.z, v0.w, w0, true);
    w1 = __builtin_amdgcn_cvt_pk_fp8_f32(v1.x, v1.y, w1, false);
    w1 = __builtin_amdgcn_cvt_pk_fp8_f32(v1.z, v1.w, w1, true);
    uint2 o; o.x = (unsigned int)w0; o.y = (unsigned int)w1;
    int node = i >> 4, oct = i & 15;          // 16 8-col octets per row
    int q = oct >> 2, o8 = oct & 3;           // plane, octet-within-plane
    *(uint2*)(xq + (size_t)q * nN * 32 + (size_t)node * 32 + o8 * 8) = o;
}

// ---------------------------------------------------------------------------
// convertW: W f32 [k][col] -> bf16 transposed Wt [col][k]
// ---------------------------------------------------------------------------
__global__ __launch_bounds__(256) void convertW_kernel(const float* __restrict__ W,
                                                       unsigned short* __restrict__ Wt) {
    int t = blockIdx.x * 256 + threadIdx.x;   // 0..4095
    int c = t >> 5, kq = t & 31;
    bf16x8 h;
#pragma unroll
    for (int i = 0; i < 8; i++) {
        int k = kq * 8 + i;
        h[i] = (short)f2bf(W[(size_t)k * OUT_DIM + c]);
    }
    *(bf16x8*)(Wt + (size_t)c * 256 + kq * 8) = h;
}

// ---------------------------------------------------------------------------
// place: edges -> per-bucket segments. payload = (dstlocal<<17)|src.
// ---------------------------------------------------------------------------
__global__ __launch_bounds__(1024) void place_kernel(const int* __restrict__ src,
                                                     const int* __restrict__ dst,
                                                     int* __restrict__ cursor,
                                                     unsigned int* __restrict__ csr_packed,
                                                     int nE, int nb) {
    __shared__ int lcnt[2048];
    __shared__ int lbase[2048];
    const int t = threadIdx.x;
    for (int i = t; i < nb; i += 1024) lcnt[i] = 0;
    __syncthreads();
    const int e0 = blockIdx.x * 16384;
    unsigned int meta[16];
#pragma unroll
    for (int k = 0; k < 16; k++) {
        int e = e0 + k * 1024 + t;
        if (e < nE) {
            int d = dst[e];
            int bk = d >> 6, dl = d & 63;
            int r = atomicAdd(&lcnt[bk], 1);
            meta[k] = ((unsigned)bk << 20) | ((unsigned)dl << 14) | (unsigned)r;
        } else meta[k] = 0xFFFFFFFFu;
    }
    __syncthreads();
    for (int i = t; i < nb; i += 1024) {
        int c = lcnt[i];
        lbase[i] = c ? atomicAdd(&cursor[i], c) : 0;
    }
    __syncthreads();
#pragma unroll
    for (int k = 0; k < 16; k++) {
        if (meta[k] != 0xFFFFFFFFu) {
            int e = e0 + k * 1024 + t;
            unsigned int m = meta[k];
            int bk = m >> 20, dl = (m >> 14) & 63, r = m & 0x3FFF;
            csr_packed[lbase[bk] + r] = ((unsigned)dl << 17) | (unsigned)src[e];
        }
    }
}

// ---------------------------------------------------------------------------
// sort: per bucket, counting-sort segment IN PLACE (payload -> plain src id,
// grouped by dst-local row) + rowinfo[row] = start | (deg<<16).
// ---------------------------------------------------------------------------
__global__ __launch_bounds__(256) void sort_kernel(unsigned int* __restrict__ csr_packed,
                                                   const int* __restrict__ cursor,
                                                   unsigned int* __restrict__ rowinfo,
                                                   int nb) {
    __shared__ int bcnt[64];
    __shared__ int bexcl[64];
    __shared__ unsigned int sorted[SEGCAP];
    const int b = blockIdx.x;
    const int t = threadIdx.x;
    const int lane = t & 63;
    const int wave = t >> 6;
    const int e0 = b * SEGCAP;
    int n = cursor[b] - e0;
    if (n > SEGCAP) n = SEGCAP;

    if (t < 64) bcnt[t] = 0;
    __syncthreads();

    unsigned int pk[6]; int rk[6];
#pragma unroll
    for (int k = 0; k < 6; k++) {
        int idx = k * 256 + t;
        if (idx < n) {
            unsigned int p = csr_packed[e0 + idx];
            pk[k] = p;
            rk[k] = atomicAdd(&bcnt[(p >> 17) & 63], 1);
        } else pk[k] = 0xFFFFFFFFu;
    }
    __syncthreads();

    if (wave == 0) {
        int v = bcnt[lane];
        int s = v;
#pragma unroll
        for (int off = 1; off < 64; off <<= 1) {
            int u = __shfl_up(s, off);
            if (lane >= off) s += u;
        }
        bexcl[lane] = s - v;
    }
    __syncthreads();

#pragma unroll
    for (int k = 0; k < 6; k++) {
        if (pk[k] != 0xFFFFFFFFu) {
            int dl = (pk[k] >> 17) & 63;
            sorted[bexcl[dl] + rk[k]] = pk[k] & 0x1FFFFu;
        }
    }
    __syncthreads();

#pragma unroll
    for (int k = 0; k < 6; k++) {
        int idx = k * 256 + t;
        if (idx < n) csr_packed[e0 + idx] = sorted[idx];
    }
    if (t < 64) rowinfo[b * 64 + t] = (unsigned)bexcl[t] | ((unsigned)bcnt[t] << 16);
}

// ---------------------------------------------------------------------------
// qgather: block = (bucket, column-quarter), XCD-pinned via blockIdx&7.
// Each XCD only reads ONE 3.2MB plane -> L2-resident after warmup.
// Wave: 8 rows in parallel (8 lanes/row, 4B = 4 fp8 cols per lane).
// ---------------------------------------------------------------------------
__global__ __launch_bounds__(256, 8) void qgather_kernel(const unsigned char* __restrict__ xq,
                                                         const unsigned int* __restrict__ csr_packed,
                                                         const unsigned int* __restrict__ rowinfo,
                                                         unsigned short* __restrict__ neigh,
                                                         int nN, int nb) {
    __shared__ unsigned int el[SEGCAP];
    __shared__ int bst[64];
    __shared__ int bdg[64];

    const int bid = blockIdx.x;
    const int xcd = bid & 7;
    const int quarter = xcd & 3;
    const int bucket = (bid >> 3) * 2 + (xcd >> 2);
    if (bucket >= nb) return;

    const int t = threadIdx.x;
    const int lane = t & 63;
    const int wave = t >> 6;

    if (t < 64) {
        unsigned int ri = rowinfo[bucket * 64 + t];
        bst[t] = (int)(ri & 0xFFFFu);
        bdg[t] = (int)(ri >> 16);
    }
    const int e0 = bucket * SEGCAP;
#pragma unroll
    for (int k = 0; k < 6; k++) {
        int idx = k * 256 + t;
        el[idx] = csr_packed[e0 + idx];
    }
    __syncthreads();

    const unsigned char* plane = xq + (size_t)quarter * nN * 32;
    const int g = lane >> 3;   // row group 0..7
    const int c = lane & 7;    // col quad (4 fp8) 0..7
    const int qoff = quarter * 32;

#pragma unroll
    for (int set = 0; set < 2; set++) {
        const int r  = wave * 16 + set * 8 + g;
        const int st = bst[r];
        const int dg = bdg[r];
        const int dgm1 = (dg > 0) ? (dg - 1) : 0;
        int maxdg = dg;
        maxdg = max(maxdg, __shfl_xor(maxdg, 8));
        maxdg = max(maxdg, __shfl_xor(maxdg, 16));
        maxdg = max(maxdg, __shfl_xor(maxdg, 32));
        f32x2 a0{0.f, 0.f}, a1{0.f, 0.f};
        for (int j = 0; j < maxdg; j += 8) {
#pragma unroll
            for (int u = 0; u < 8; u++) {
                const int id  = j + u;
                const int cid = (id < dg) ? id : dgm1;
                int s = (int)el[st + cid];
                unsigned int v = *(const unsigned int*)(plane + (size_t)s * 32 + c * 4);
                v = (id < dg) ? v : 0u;
                f32x2 p;
                p = __builtin_amdgcn_cvt_pk_f32_fp8(v, false); a0 += p;
                p = __builtin_amdgcn_cvt_pk_f32_fp8(v, true);  a1 += p;
            }
        }
        const float rd = 1.0f / (float)((dg > 0) ? dg : 1);
        a0 *= rd; a1 *= rd;
        unsigned int w0, w1;
        asm("v_cvt_pk_bf16_f32 %0, %1, %2" : "=v"(w0) : "v"(a0.x), "v"(a0.y));
        asm("v_cvt_pk_bf16_f32 %0, %1, %2" : "=v"(w1) : "v"(a1.x), "v"(a1.y));
        uint2 o; o.x = w0; o.y = w1;
        const int row = bucket * 64 + r;   // rows >= nN land in allocated pad
        *(uint2*)(neigh + (size_t)row * IN_DIM + qoff + c * 4) = o;
    }
}

// ---------------------------------------------------------------------------
// gemm: r11-proven (LDS-staged A + direct-copy staged pre-transposed Wt)
// ---------------------------------------------------------------------------
__global__ __launch_bounds__(256, 3) void gemm_kernel(const float* __restrict__ x,
                                                      const unsigned short* __restrict__ neigh,
                                                      const unsigned short* __restrict__ Wt,
                                                      const float* __restrict__ bias,
                                                      float* __restrict__ out, int nN) {
    __shared__ __align__(16) short A_s[64 * 264];
    __shared__ __align__(16) short Wt_s[128 * 72];

    const int t = threadIdx.x;
    const int lane = t & 63;
    const int wave = t >> 6;
    const int row0 = blockIdx.x * 64;

#pragma unroll
    for (int p = 0; p < 8; p++) {
        int q = t + p * 256;
        int r = q >> 5, c4 = q & 31;
        int row = row0 + r;
        float4 v = make_float4(0.f, 0.f, 0.f, 0.f);
        if (row < nN) v = *(const float4*)(x + (size_t)row * IN_DIM + c4 * 4);
        unsigned int lo = (unsigned int)f2bf(v.x) | ((unsigned int)f2bf(v.y) << 16);
        unsigned int hi = (unsigned int)f2bf(v.z) | ((unsigned int)f2bf(v.w) << 16);
        uint2 o; o.x = lo; o.y = hi;
        *(uint2*)&A_s[r * 264 + c4 * 4] = o;
    }
#pragma unroll
    for (int p = 0; p < 4; p++) {
        int q = t + p * 256;
        int r = q >> 4, c8 = q & 15;
        int row = row0 + r;
        bf16x8 v = {0, 0, 0, 0, 0, 0, 0, 0};
        if (row < nN) v = *(const bf16x8*)(neigh + (size_t)row * IN_DIM + c8 * 8);
        *(bf16x8*)&A_s[r * 264 + 128 + c8 * 8] = v;
    }

    f32x4 acc[8];
#pragma unroll
    for (int c = 0; c < 8; c++) acc[c] = f32x4{0.f, 0.f, 0.f, 0.f};

    const int arow = wave * 16 + (lane & 15);
    const int koff = (lane >> 4) * 8;

    for (int kc = 0; kc < 4; kc++) {
        __syncthreads();
#pragma unroll
        for (int p = 0; p < 4; p++) {
            int q = t + p * 256;
            int col = q >> 3, ko = q & 7;
            *(bf16x8*)&Wt_s[col * 72 + ko * 8] =
                *(const bf16x8*)(Wt + (size_t)col * 256 + kc * 64 + ko * 8);
        }
        __syncthreads();
#pragma unroll
        for (int ks = 0; ks < 2; ks++) {
            const int kloc = ks * 32 + koff;
            bf16x8 af = *(const bf16x8*)&A_s[arow * 264 + kc * 64 + kloc];
#pragma unroll
            for (int c = 0; c < 8; c++) {
                bf16x8 bf = *(const bf16x8*)&Wt_s[(c * 16 + (lane & 15)) * 72 + kloc];
                acc[c] = __builtin_amdgcn_mfma_f32_16x16x32_bf16(af, bf, acc[c], 0, 0, 0);
            }
        }
    }

    const int orow0 = row0 + wave * 16 + (lane >> 4) * 4;
    const int ocol  = lane & 15;
#pragma unroll
    for (int c = 0; c < 8; c++) {
        const float bv = bias[c * 16 + ocol];
#pragma unroll
        for (int r = 0; r < 4; r++) {
            int row = orow0 + r;
            if (row < nN)
                out[(size_t)row * OUT_DIM + c * 16 + ocol] = acc[c][r] + bv;
        }
    }
}

// ---------------------------------------------------------------------------
extern "C" void kernel_launch(void* const* d_in, const int* in_sizes, int n_in,
                              void* d_out, int out_size, void* d_ws, size_t ws_size,
                              hipStream_t stream) {
    const float* x        = (const float*)d_in[0];
    const int*   edge_src = (const int*)d_in[1];
    const int*   edge_dst = (const int*)d_in[2];
    const float* W        = (const float*)d_in[3];
    const float* bias     = (const float*)d_in[4];
    float* out = (float*)d_out;

    const int nN = in_sizes[0] / IN_DIM;   // 100000
    const int nE = in_sizes[1];            // 1600000
    const int nb = (nN + 63) >> 6;         // 1563 buckets

    // ws (~48.5 MB): cursor[2048], csr_packed[nb*SEGCAP] u32 (9.6MB),
    //   rowinfo[nb*64] u32 (0.4MB), xq 4 planes [nN][32] fp8 (12.8MB),
    //   Wt bf16 (64KB), neigh bf16[nb*64*128] (25.6MB)
    int* cursor = (int*)d_ws;
    unsigned int* csr_packed = (unsigned int*)(cursor + 2048);
    unsigned int* rowinfo = csr_packed + (size_t)nb * SEGCAP;
    unsigned char* xq = (unsigned char*)(rowinfo + (size_t)nb * 64);
    unsigned short* Wt = (unsigned short*)(xq + (size_t)nN * IN_DIM);
    unsigned short* neigh = Wt + 128 * 256;

    init_kernel<<<(nb + 255) / 256, 256, 0, stream>>>(cursor, nb);

    const int total8 = nN * IN_DIM / 8;
    convertq_kernel<<<(total8 + 255) / 256, 256, 0, stream>>>(x, xq, nN, total8);
    convertW_kernel<<<16, 256, 0, stream>>>(W, Wt);

    const int eblk = (nE + 16383) / 16384;   // 98
    place_kernel<<<eblk, 1024, 0, stream>>>(edge_src, edge_dst, cursor, csr_packed, nE, nb);
    sort_kernel<<<nb, 256, 0, stream>>>(csr_packed, cursor, rowinfo, nb);

    const int nbp2 = (nb + 1) / 2;           // 782
    qgather_kernel<<<nbp2 * 8, 256, 0, stream>>>(xq, csr_packed, rowinfo, neigh, nN, nb);
    gemm_kernel<<<nb, 256, 0, stream>>>(x, neigh, Wt, bias, out, nN);
}

// Round 13
// 118.615 us; speedup vs baseline: 1.5955x; 1.1363x over previous
//
#include <hip/hip_runtime.h>

#define IN_DIM 128
#define OUT_DIM 128
#define SEGCAP 1536   // per-bucket segment capacity (Poisson(1024), 16-sigma safe)
#define EPB 8192      // edges per place block

typedef short bf16x8 __attribute__((ext_vector_type(8)));
typedef float f32x4 __attribute__((ext_vector_type(4)));
typedef float f32x2 __attribute__((ext_vector_type(2)));

__device__ __forceinline__ unsigned short f2bf(float f) {
    union { float f; unsigned int u; } v; v.f = f;
    unsigned int u = v.u;
    u += 0x7FFFu + ((u >> 16) & 1u);   // round-to-nearest-even
    return (unsigned short)(u >> 16);
}

// ---------------------------------------------------------------------------
// init: cursor[i] = i*SEGCAP
// ---------------------------------------------------------------------------
__global__ __launch_bounds__(256) void init_kernel(int* __restrict__ cursor, int nb) {
    int i = blockIdx.x * 256 + threadIdx.x;
    if (i < nb) cursor[i] = i * SEGCAP;
}

// ---------------------------------------------------------------------------
// convertq: x f32 -> fp8 e4m3, 4 column-quarter PLANES [nN][32] (3.2MB each).
// ---------------------------------------------------------------------------
__global__ __launch_bounds__(256) void convertq_kernel(const float* __restrict__ x,
                                                       unsigned char* __restrict__ xq,
                                                       int nN, int total8) {
    int i = blockIdx.x * 256 + threadIdx.x;
    if (i >= total8) return;
    const float4* p = (const float4*)x + (size_t)i * 2;
    float4 v0 = p[0], v1 = p[1];
    int w0 = 0, w1 = 0;
    w0 = __builtin_amdgcn_cvt_pk_fp8_f32(v0.x, v0.y, w0, false);
    w0 = __builtin_amdgcn_cvt_pk_fp8_f32(v0.z, v0.w, w0, true);
    w1 = __builtin_amdgcn_cvt_pk_fp8_f32(v1.x, v1.y, w1, false);
    w1 = __builtin_amdgcn_cvt_pk_fp8_f32(v1.z, v1.w, w1, true);
    uint2 o; o.x = (unsigned int)w0; o.y = (unsigned int)w1;
    int node = i >> 4, oct = i & 15;
    int q = oct >> 2, o8 = oct & 3;
    *(uint2*)(xq + (size_t)q * nN * 32 + (size_t)node * 32 + o8 * 8) = o;
}

// ---------------------------------------------------------------------------
// convertW: W f32 [k][col] -> bf16 in MFMA FRAGMENT layout:
//   WF[(f*8+c)*64 + lane] (16B each), f = kc*2+ks.
//   Fragment (f,c), lane l covers col = c*16+(l&15), k = f*32+(l>>4)*8 ..+8.
// ---------------------------------------------------------------------------
__global__ __launch_bounds__(256) void convertW_kernel(const float* __restrict__ W,
                                                       unsigned short* __restrict__ WF) {
    int t = blockIdx.x * 256 + threadIdx.x;   // 0..4095
    int frag = t >> 6, lane = t & 63;         // frag = f*8+c
    int f = frag >> 3, c = frag & 7;
    int col = c * 16 + (lane & 15);
    int kbase = f * 32 + (lane >> 4) * 8;
    bf16x8 h;
#pragma unroll
    for (int i = 0; i < 8; i++)
        h[i] = (short)f2bf(W[(size_t)(kbase + i) * OUT_DIM + col]);
    *(bf16x8*)(WF + (size_t)t * 8) = h;
}

// ---------------------------------------------------------------------------
// place: edges -> per-bucket segments. payload = (dstlocal<<17)|src.
// 196 blocks x 8192 edges (was 98x16384): 2x CU coverage.
// ---------------------------------------------------------------------------
__global__ __launch_bounds__(1024) void place_kernel(const int* __restrict__ src,
                                                     const int* __restrict__ dst,
                                                     int* __restrict__ cursor,
                                                     unsigned int* __restrict__ csr_packed,
                                                     int nE, int nb) {
    __shared__ int lcnt[2048];
    __shared__ int lbase[2048];
    const int t = threadIdx.x;
    for (int i = t; i < nb; i += 1024) lcnt[i] = 0;
    __syncthreads();
    const int e0 = blockIdx.x * EPB;
    unsigned int meta[EPB / 1024];
#pragma unroll
    for (int k = 0; k < EPB / 1024; k++) {
        int e = e0 + k * 1024 + t;
        if (e < nE) {
            int d = dst[e];
            int bk = d >> 6, dl = d & 63;
            int r = atomicAdd(&lcnt[bk], 1);
            meta[k] = ((unsigned)bk << 20) | ((unsigned)dl << 14) | (unsigned)r;
        } else meta[k] = 0xFFFFFFFFu;
    }
    __syncthreads();
    for (int i = t; i < nb; i += 1024) {
        int c = lcnt[i];
        lbase[i] = c ? atomicAdd(&cursor[i], c) : 0;
    }
    __syncthreads();
#pragma unroll
    for (int k = 0; k < EPB / 1024; k++) {
        if (meta[k] != 0xFFFFFFFFu) {
            int e = e0 + k * 1024 + t;
            unsigned int m = meta[k];
            int bk = m >> 20, dl = (m >> 14) & 63, r = m & 0x3FFF;
            csr_packed[lbase[bk] + r] = ((unsigned)dl << 17) | (unsigned)src[e];
        }
    }
}

// ---------------------------------------------------------------------------
// sort: per bucket, counting-sort segment in place + rowinfo = start|(deg<<16)
// ---------------------------------------------------------------------------
__global__ __launch_bounds__(256) void sort_kernel(unsigned int* __restrict__ csr_packed,
                                                   const int* __restrict__ cursor,
                                                   unsigned int* __restrict__ rowinfo,
                                                   int nb) {
    __shared__ int bcnt[64];
    __shared__ int bexcl[64];
    __shared__ unsigned int sorted[SEGCAP];
    const int b = blockIdx.x;
    const int t = threadIdx.x;
    const int lane = t & 63;
    const int wave = t >> 6;
    const int e0 = b * SEGCAP;
    int n = cursor[b] - e0;
    if (n > SEGCAP) n = SEGCAP;

    if (t < 64) bcnt[t] = 0;
    __syncthreads();

    unsigned int pk[6]; int rk[6];
#pragma unroll
    for (int k = 0; k < 6; k++) {
        int idx = k * 256 + t;
        if (idx < n) {
            unsigned int p = csr_packed[e0 + idx];
            pk[k] = p;
            rk[k] = atomicAdd(&bcnt[(p >> 17) & 63], 1);
        } else pk[k] = 0xFFFFFFFFu;
    }
    __syncthreads();

    if (wave == 0) {
        int v = bcnt[lane];
        int s = v;
#pragma unroll
        for (int off = 1; off < 64; off <<= 1) {
            int u = __shfl_up(s, off);
            if (lane >= off) s += u;
        }
        bexcl[lane] = s - v;
    }
    __syncthreads();

#pragma unroll
    for (int k = 0; k < 6; k++) {
        if (pk[k] != 0xFFFFFFFFu) {
            int dl = (pk[k] >> 17) & 63;
            sorted[bexcl[dl] + rk[k]] = pk[k] & 0x1FFFFu;
        }
    }
    __syncthreads();

#pragma unroll
    for (int k = 0; k < 6; k++) {
        int idx = k * 256 + t;
        if (idx < n) csr_packed[e0 + idx] = sorted[idx];
    }
    if (t < 64) rowinfo[b * 64 + t] = (unsigned)bexcl[t] | ((unsigned)bcnt[t] << 16);
}

// ---------------------------------------------------------------------------
// qgather: block = (bucket, column-quarter), XCD-pinned -> plane L2-resident.
// ---------------------------------------------------------------------------
__global__ __launch_bounds__(256, 8) void qgather_kernel(const unsigned char* __restrict__ xq,
                                                         const unsigned int* __restrict__ csr_packed,
                                                         const unsigned int* __restrict__ rowinfo,
                                                         unsigned short* __restrict__ neigh,
                                                         int nN, int nb) {
    __shared__ unsigned int el[SEGCAP];
    __shared__ int bst[64];
    __shared__ int bdg[64];

    const int bid = blockIdx.x;
    const int xcd = bid & 7;
    const int quarter = xcd & 3;
    const int bucket = (bid >> 3) * 2 + (xcd >> 2);
    if (bucket >= nb) return;

    const int t = threadIdx.x;
    const int lane = t & 63;
    const int wave = t >> 6;

    if (t < 64) {
        unsigned int ri = rowinfo[bucket * 64 + t];
        bst[t] = (int)(ri & 0xFFFFu);
        bdg[t] = (int)(ri >> 16);
    }
    const int e0 = bucket * SEGCAP;
#pragma unroll
    for (int k = 0; k < 6; k++) {
        int idx = k * 256 + t;
        el[idx] = csr_packed[e0 + idx];
    }
    __syncthreads();

    const unsigned char* plane = xq + (size_t)quarter * nN * 32;
    const int g = lane >> 3;
    const int c = lane & 7;
    const int qoff = quarter * 32;

#pragma unroll
    for (int set = 0; set < 2; set++) {
        const int r  = wave * 16 + set * 8 + g;
        const int st = bst[r];
        const int dg = bdg[r];
        const int dgm1 = (dg > 0) ? (dg - 1) : 0;
        int maxdg = dg;
        maxdg = max(maxdg, __shfl_xor(maxdg, 8));
        maxdg = max(maxdg, __shfl_xor(maxdg, 16));
        maxdg = max(maxdg, __shfl_xor(maxdg, 32));
        f32x2 a0{0.f, 0.f}, a1{0.f, 0.f};
        for (int j = 0; j < maxdg; j += 8) {
#pragma unroll
            for (int u = 0; u < 8; u++) {
                const int id  = j + u;
                const int cid = (id < dg) ? id : dgm1;
                int s = (int)el[st + cid];
                unsigned int v = *(const unsigned int*)(plane + (size_t)s * 32 + c * 4);
                v = (id < dg) ? v : 0u;
                f32x2 p;
                p = __builtin_amdgcn_cvt_pk_f32_fp8(v, false); a0 += p;
                p = __builtin_amdgcn_cvt_pk_f32_fp8(v, true);  a1 += p;
            }
        }
        const float rd = 1.0f / (float)((dg > 0) ? dg : 1);
        a0 *= rd; a1 *= rd;
        unsigned int w0, w1;
        asm("v_cvt_pk_bf16_f32 %0, %1, %2" : "=v"(w0) : "v"(a0.x), "v"(a0.y));
        asm("v_cvt_pk_bf16_f32 %0, %1, %2" : "=v"(w1) : "v"(a1.x), "v"(a1.y));
        uint2 o; o.x = w0; o.y = w1;
        const int row = bucket * 64 + r;
        *(uint2*)(neigh + (size_t)row * IN_DIM + qoff + c * 4) = o;
    }
}

// ---------------------------------------------------------------------------
// gemm: ZERO-LDS ZERO-BARRIER streaming GEMM.
//   A x-half: per-lane direct f32 loads + cvt_pk_bf16 (same rounding as f2bf).
//   A neigh-half: per-lane direct bf16 16B loads.
//   B: fragment-layout WF — each read is a wave-contiguous 1KB L2-resident load.
// ---------------------------------------------------------------------------
__global__ __launch_bounds__(256, 6) void gemm_kernel(const float* __restrict__ x,
                                                      const unsigned short* __restrict__ neigh,
                                                      const unsigned short* __restrict__ WF,
                                                      const float* __restrict__ bias,
                                                      float* __restrict__ out, int nN) {
    const int t = threadIdx.x;
    const int lane = t & 63;
    const int wave = t >> 6;
    const int row0 = blockIdx.x * 64;

    f32x4 acc[8];
#pragma unroll
    for (int c = 0; c < 8; c++) acc[c] = f32x4{0.f, 0.f, 0.f, 0.f};

    const int arow = wave * 16 + (lane & 15);
    const int koff = (lane >> 4) * 8;
    const int rowc = min(row0 + arow, nN - 1);   // clamp: OOB rows never stored
    const float*          xrow = x     + (size_t)rowc * IN_DIM;
    const unsigned short* nrow = neigh + (size_t)rowc * IN_DIM;

#pragma unroll
    for (int f = 0; f < 8; f++) {
        bf16x8 af;
        if (f < 4) {
            const float* px = xrow + f * 32 + koff;
            float4 v0 = *(const float4*)px;
            float4 v1 = *(const float4*)(px + 4);
            unsigned int r0, r1, r2, r3;
            asm("v_cvt_pk_bf16_f32 %0, %1, %2" : "=v"(r0) : "v"(v0.x), "v"(v0.y));
            asm("v_cvt_pk_bf16_f32 %0, %1, %2" : "=v"(r1) : "v"(v0.z), "v"(v0.w));
            asm("v_cvt_pk_bf16_f32 %0, %1, %2" : "=v"(r2) : "v"(v1.x), "v"(v1.y));
            asm("v_cvt_pk_bf16_f32 %0, %1, %2" : "=v"(r3) : "v"(v1.z), "v"(v1.w));
            union { unsigned int u[4]; bf16x8 v; } cv;
            cv.u[0] = r0; cv.u[1] = r1; cv.u[2] = r2; cv.u[3] = r3;
            af = cv.v;
        } else {
            af = *(const bf16x8*)(nrow + (f - 4) * 32 + koff);
        }
#pragma unroll
        for (int c = 0; c < 8; c++) {
            bf16x8 bf = *(const bf16x8*)(WF + ((size_t)(f * 8 + c) * 64 + lane) * 8);
            acc[c] = __builtin_amdgcn_mfma_f32_16x16x32_bf16(af, bf, acc[c], 0, 0, 0);
        }
    }

    // epilogue: C/D layout col=lane&15, row=(lane>>4)*4+reg  [m89]
    const int orow0 = row0 + wave * 16 + (lane >> 4) * 4;
    const int ocol  = lane & 15;
#pragma unroll
    for (int c = 0; c < 8; c++) {
        const float bv = bias[c * 16 + ocol];
#pragma unroll
        for (int r = 0; r < 4; r++) {
            int row = orow0 + r;
            if (row < nN)
                out[(size_t)row * OUT_DIM + c * 16 + ocol] = acc[c][r] + bv;
        }
    }
}

// ---------------------------------------------------------------------------
extern "C" void kernel_launch(void* const* d_in, const int* in_sizes, int n_in,
                              void* d_out, int out_size, void* d_ws, size_t ws_size,
                              hipStream_t stream) {
    const float* x        = (const float*)d_in[0];
    const int*   edge_src = (const int*)d_in[1];
    const int*   edge_dst = (const int*)d_in[2];
    const float* W        = (const float*)d_in[3];
    const float* bias     = (const float*)d_in[4];
    float* out = (float*)d_out;

    const int nN = in_sizes[0] / IN_DIM;   // 100000
    const int nE = in_sizes[1];            // 1600000
    const int nb = (nN + 63) >> 6;         // 1563 buckets

    // ws (~48.5 MB): cursor[2048], csr_packed[nb*SEGCAP] u32 (9.6MB),
    //   rowinfo[nb*64] u32 (0.4MB), xq 4 planes (12.8MB), WF bf16 (64KB),
    //   neigh bf16[nb*64*128] (25.6MB)
    int* cursor = (int*)d_ws;
    unsigned int* csr_packed = (unsigned int*)(cursor + 2048);
    unsigned int* rowinfo = csr_packed + (size_t)nb * SEGCAP;
    unsigned char* xq = (unsigned char*)(rowinfo + (size_t)nb * 64);
    unsigned short* WF = (unsigned short*)(xq + (size_t)nN * IN_DIM);
    unsigned short* neigh = WF + 128 * 256;

    init_kernel<<<(nb + 255) / 256, 256, 0, stream>>>(cursor, nb);

    const int total8 = nN * IN_DIM / 8;
    convertq_kernel<<<(total8 + 255) / 256, 256, 0, stream>>>(x, xq, nN, total8);
    convertW_kernel<<<16, 256, 0, stream>>>(W, WF);

    const int eblk = (nE + EPB - 1) / EPB;   // 196
    place_kernel<<<eblk, 1024, 0, stream>>>(edge_src, edge_dst, cursor, csr_packed, nE, nb);
    sort_kernel<<<nb, 256, 0, stream>>>(csr_packed, cursor, rowinfo, nb);

    const int nbp2 = (nb + 1) / 2;           // 782
    qgather_kernel<<<nbp2 * 8, 256, 0, stream>>>(xq, csr_packed, rowinfo, neigh, nN, nb);
    gemm_kernel<<<(nN + 63) / 64, 256, 0, stream>>>(x, neigh, WF, bias, out, nN);
}